// Round 1
// baseline (5016.172 us; speedup 1.0000x reference)
//
#include <hip/hip_runtime.h>

#define N_NODES 100000
#define N_EDGES 1600000
#define F_IN    512
#define HIDDEN  16
#define N_CLS   40

// ---------------- degree ----------------
__global__ void k_init_deg(float* __restrict__ deg) {
    int i = blockIdx.x * blockDim.x + threadIdx.x;
    if (i < N_NODES) deg[i] = 1.0f;   // self-loop
}

__global__ void k_count_deg(const int* __restrict__ ei, float* __restrict__ deg) {
    int e = blockIdx.x * blockDim.x + threadIdx.x;
    if (e < N_EDGES) atomicAdd(&deg[ei[N_EDGES + e]], 1.0f);  // col = ei[1][e]
}

__global__ void k_finish_dis(float* __restrict__ deg) {
    int i = blockIdx.x * blockDim.x + threadIdx.x;
    if (i < N_NODES) deg[i] = rsqrtf(deg[i]);   // deg >= 1 always
}

// ---------------- layer-1 GEMM: h1s = (x @ W1) * dis ; agg1 init = self-loop ----
__global__ __launch_bounds__(256) void k_gemm1(
        const float* __restrict__ x, const float* __restrict__ W1,
        const float* __restrict__ dis,
        float* __restrict__ h1s, float* __restrict__ agg1) {
    __shared__ float sW[F_IN * HIDDEN];            // 32 KB
    {
        const float4* Wv = (const float4*)W1;
        float4* sWv = (float4*)sW;
        for (int idx = threadIdx.x; idx < F_IN * HIDDEN / 4; idx += 256)
            sWv[idx] = Wv[idx];
    }
    __syncthreads();

    int row = blockIdx.x * 256 + threadIdx.x;
    if (row >= N_NODES) return;

    float acc[HIDDEN];
#pragma unroll
    for (int j = 0; j < HIDDEN; ++j) acc[j] = 0.0f;

    const float* xr = x + (size_t)row * F_IN;
#pragma unroll 4
    for (int k = 0; k < F_IN; k += 4) {
        float4 xv = *(const float4*)(xr + k);
        const float xs[4] = {xv.x, xv.y, xv.z, xv.w};
#pragma unroll
        for (int kk = 0; kk < 4; ++kk) {
            const float* wrow = &sW[(k + kk) * HIDDEN];
#pragma unroll
            for (int j = 0; j < HIDDEN; ++j)
                acc[j] = fmaf(xs[kk], wrow[j], acc[j]);
        }
    }

    float d = dis[row];
    float* h = h1s + (size_t)row * HIDDEN;
    float* a = agg1 + (size_t)row * HIDDEN;
#pragma unroll
    for (int q = 0; q < 4; ++q) {
        float4 hv, av;
        hv.x = acc[q*4+0] * d;  hv.y = acc[q*4+1] * d;
        hv.z = acc[q*4+2] * d;  hv.w = acc[q*4+3] * d;
        av.x = hv.x * d; av.y = hv.y * d; av.z = hv.z * d; av.w = hv.w * d;
        *(float4*)(h + q*4) = hv;        // h1[row]*dis[row]
        *(float4*)(a + q*4) = av;        // self-loop term h1s*dis
    }
}

// ---------------- scatter layer 1: agg1[c] += h1s[r] * dis[c] ----------------
__global__ void k_scatter1(const int* __restrict__ ei, const float* __restrict__ dis,
                           const float* __restrict__ h1s, float* __restrict__ agg1) {
    int e = blockIdx.x * blockDim.x + threadIdx.x;
    if (e >= N_EDGES) return;
    int r = ei[e];
    int c = ei[N_EDGES + e];
    float dc = dis[c];
    const float4* src = (const float4*)(h1s + (size_t)r * HIDDEN);
    float* dst = agg1 + (size_t)c * HIDDEN;
#pragma unroll
    for (int q = 0; q < 4; ++q) {
        float4 v = src[q];
        atomicAdd(dst + q*4 + 0, v.x * dc);
        atomicAdd(dst + q*4 + 1, v.y * dc);
        atomicAdd(dst + q*4 + 2, v.z * dc);
        atomicAdd(dst + q*4 + 3, v.w * dc);
    }
}

// ---------------- layer 2: relu(agg1+b1) @ W2 -> h2s, out init ----------------
__global__ __launch_bounds__(256) void k_layer2(
        const float* __restrict__ agg1, const float* __restrict__ W2,
        const float* __restrict__ b1, const float* __restrict__ b2,
        const float* __restrict__ dis,
        float* __restrict__ h2s, float* __restrict__ out) {
    __shared__ float sW[HIDDEN * N_CLS];
    __shared__ float sb1[HIDDEN];
    __shared__ float sb2[N_CLS];
    for (int idx = threadIdx.x; idx < HIDDEN * N_CLS; idx += 256) sW[idx] = W2[idx];
    if (threadIdx.x < HIDDEN) sb1[threadIdx.x] = b1[threadIdx.x];
    if (threadIdx.x < N_CLS)  sb2[threadIdx.x] = b2[threadIdx.x];
    __syncthreads();

    int i = blockIdx.x * 256 + threadIdx.x;
    if (i >= N_NODES) return;

    float a[HIDDEN];
    const float4* ar = (const float4*)(agg1 + (size_t)i * HIDDEN);
#pragma unroll
    for (int q = 0; q < 4; ++q) {
        float4 v = ar[q];
        a[q*4+0] = fmaxf(v.x + sb1[q*4+0], 0.0f);
        a[q*4+1] = fmaxf(v.y + sb1[q*4+1], 0.0f);
        a[q*4+2] = fmaxf(v.z + sb1[q*4+2], 0.0f);
        a[q*4+3] = fmaxf(v.w + sb1[q*4+3], 0.0f);
    }

    float o[N_CLS];
#pragma unroll
    for (int k = 0; k < N_CLS; ++k) o[k] = 0.0f;
#pragma unroll
    for (int j = 0; j < HIDDEN; ++j) {
        float aj = a[j];
        const float* wrow = &sW[j * N_CLS];
#pragma unroll
        for (int k = 0; k < N_CLS; ++k)
            o[k] = fmaf(aj, wrow[k], o[k]);
    }

    float d = dis[i];
    float* hp = h2s + (size_t)i * N_CLS;
    float* op = out + (size_t)i * N_CLS;
#pragma unroll
    for (int q = 0; q < 10; ++q) {
        float4 hv, ov;
        hv.x = o[q*4+0] * d;  hv.y = o[q*4+1] * d;
        hv.z = o[q*4+2] * d;  hv.w = o[q*4+3] * d;
        // out init = bias + self-loop contribution h2s*dis
        ov.x = fmaf(hv.x, d, sb2[q*4+0]);
        ov.y = fmaf(hv.y, d, sb2[q*4+1]);
        ov.z = fmaf(hv.z, d, sb2[q*4+2]);
        ov.w = fmaf(hv.w, d, sb2[q*4+3]);
        *(float4*)(hp + q*4) = hv;
        *(float4*)(op + q*4) = ov;
    }
}

// ---------------- scatter layer 2: out[c] += h2s[r] * dis[c] ----------------
__global__ void k_scatter2(const int* __restrict__ ei, const float* __restrict__ dis,
                           const float* __restrict__ h2s, float* __restrict__ out) {
    int e = blockIdx.x * blockDim.x + threadIdx.x;
    if (e >= N_EDGES) return;
    int r = ei[e];
    int c = ei[N_EDGES + e];
    float dc = dis[c];
    const float4* src = (const float4*)(h2s + (size_t)r * N_CLS);
    float* dst = out + (size_t)c * N_CLS;
#pragma unroll
    for (int q = 0; q < 10; ++q) {
        float4 v = src[q];
        atomicAdd(dst + q*4 + 0, v.x * dc);
        atomicAdd(dst + q*4 + 1, v.y * dc);
        atomicAdd(dst + q*4 + 2, v.z * dc);
        atomicAdd(dst + q*4 + 3, v.w * dc);
    }
}

extern "C" void kernel_launch(void* const* d_in, const int* in_sizes, int n_in,
                              void* d_out, int out_size, void* d_ws, size_t ws_size,
                              hipStream_t stream) {
    const float* x  = (const float*)d_in[0];
    const int*   ei = (const int*)d_in[1];     // [2, E] row-major: row=ei[0..E), col=ei[E..2E)
    const float* W1 = (const float*)d_in[2];
    const float* b1 = (const float*)d_in[3];
    const float* W2 = (const float*)d_in[4];
    const float* b2 = (const float*)d_in[5];
    float* out = (float*)d_out;

    // workspace layout (floats): dis[N] | h1s[N*16] | agg1[N*16] | h2s[N*40]
    float* ws   = (float*)d_ws;
    float* dis  = ws;                                  // 100000
    float* h1s  = ws + N_NODES;                        // 1.6M
    float* agg1 = h1s + (size_t)N_NODES * HIDDEN;      // 1.6M
    float* h2s  = agg1 + (size_t)N_NODES * HIDDEN;     // 4.0M   (total 29.2 MB)

    const int TB = 256;
    const int gN = (N_NODES + TB - 1) / TB;
    const int gE = (N_EDGES + TB - 1) / TB;

    k_init_deg  <<<gN, TB, 0, stream>>>(dis);
    k_count_deg <<<gE, TB, 0, stream>>>(ei, dis);
    k_finish_dis<<<gN, TB, 0, stream>>>(dis);
    k_gemm1     <<<gN, TB, 0, stream>>>(x, W1, dis, h1s, agg1);
    k_scatter1  <<<gE, TB, 0, stream>>>(ei, dis, h1s, agg1);
    k_layer2    <<<gN, TB, 0, stream>>>(agg1, W2, b1, b2, dis, h2s, out);
    k_scatter2  <<<gE, TB, 0, stream>>>(ei, dis, h2s, out);
}

// Round 2
// 563.129 us; speedup vs baseline: 8.9077x; 8.9077x over previous
//
#include <hip/hip_runtime.h>

#define N_NODES 100000
#define N_EDGES 1600000
#define F_IN    512
#define HIDDEN  16
#define N_CLS   40
#define NSB     ((N_NODES + 1023) / 1024)   // scan blocks (98)

// ---------------- zero int counts ----------------
__global__ void k_zero(int* __restrict__ cnt) {
    int i = blockIdx.x * blockDim.x + threadIdx.x;
    if (i < N_NODES) cnt[i] = 0;
}

// ---------------- in-degree histogram (int atomics) ----------------
__global__ void k_count(const int* __restrict__ ei, int* __restrict__ cnt) {
    int e = blockIdx.x * blockDim.x + threadIdx.x;
    if (e < N_EDGES) atomicAdd(&cnt[ei[N_EDGES + e]], 1);
}

// ---------------- scan pass A: per-block sums (1024 elems / block) --------
__global__ __launch_bounds__(256) void k_scanA(const int* __restrict__ cnt,
                                               int* __restrict__ blockSums) {
    __shared__ int s[256];
    int t = threadIdx.x;
    int base = blockIdx.x * 1024 + t * 4;
    int v = 0;
    if (base + 3 < N_NODES) {
        int4 c = *(const int4*)(cnt + base);
        v = c.x + c.y + c.z + c.w;
    } else {
        for (int i = 0; i < 4; ++i) { int idx = base + i; if (idx < N_NODES) v += cnt[idx]; }
    }
    s[t] = v; __syncthreads();
    for (int off = 128; off > 0; off >>= 1) {
        if (t < off) s[t] += s[t + off];
        __syncthreads();
    }
    if (t == 0) blockSums[blockIdx.x] = s[0];
}

// ---------------- scan pass B: exclusive scan of 98 block sums -----------
__global__ __launch_bounds__(128) void k_scanB(int* __restrict__ blockSums) {
    __shared__ int s[128];
    int t = threadIdx.x;
    int v = (t < NSB) ? blockSums[t] : 0;
    s[t] = v; __syncthreads();
    for (int off = 1; off < 128; off <<= 1) {
        int add = (t >= off) ? s[t - off] : 0;
        __syncthreads();
        s[t] += add;
        __syncthreads();
    }
    if (t < NSB) blockSums[t] = s[t] - v;   // exclusive
}

// ---------------- scan pass C: per-elem offsets + cursor + dis -----------
__global__ __launch_bounds__(256) void k_scanC(const int* __restrict__ cnt,
                                               const int* __restrict__ blockSums,
                                               int* __restrict__ offsets,
                                               int* __restrict__ cursor,
                                               float* __restrict__ dis) {
    __shared__ int s[256];
    int t = threadIdx.x;
    int base = blockIdx.x * 1024 + t * 4;
    int v0 = 0, v1 = 0, v2 = 0, v3 = 0;
    if (base + 3 < N_NODES) {
        int4 c = *(const int4*)(cnt + base);
        v0 = c.x; v1 = c.y; v2 = c.z; v3 = c.w;
    } else {
        if (base + 0 < N_NODES) v0 = cnt[base + 0];
        if (base + 1 < N_NODES) v1 = cnt[base + 1];
        if (base + 2 < N_NODES) v2 = cnt[base + 2];
        if (base + 3 < N_NODES) v3 = cnt[base + 3];
    }
    int tsum = v0 + v1 + v2 + v3;
    s[t] = tsum; __syncthreads();
    for (int off = 1; off < 256; off <<= 1) {
        int add = (t >= off) ? s[t - off] : 0;
        __syncthreads();
        s[t] += add;
        __syncthreads();
    }
    int o = blockSums[blockIdx.x] + s[t] - tsum;   // exclusive base for this thread
    int ov[4] = { o, o + v0, o + v0 + v1, o + v0 + v1 + v2 };
    int vv[4] = { v0, v1, v2, v3 };
    for (int i = 0; i < 4; ++i) {
        int idx = base + i;
        if (idx < N_NODES) {
            offsets[idx] = ov[i];
            cursor[idx]  = ov[i];
            dis[idx]     = rsqrtf(1.0f + (float)vv[i]);   // deg = 1 + indeg
        }
    }
}

// ---------------- CSR bucket fill ----------------
__global__ void k_fill(const int* __restrict__ ei, int* __restrict__ cursor,
                       int* __restrict__ csr) {
    int e = blockIdx.x * blockDim.x + threadIdx.x;
    if (e >= N_EDGES) return;
    int r = ei[e];
    int c = ei[N_EDGES + e];
    int pos = atomicAdd(&cursor[c], 1);
    csr[pos] = r;
}

// ---------------- layer-1 GEMM: h1s = (x @ W1) * dis ----------------
__global__ __launch_bounds__(256) void k_gemm1(
        const float* __restrict__ x, const float* __restrict__ W1,
        const float* __restrict__ dis, float* __restrict__ h1s) {
    __shared__ float sW[F_IN * HIDDEN];            // 32 KB
    {
        const float4* Wv = (const float4*)W1;
        float4* sWv = (float4*)sW;
        for (int idx = threadIdx.x; idx < F_IN * HIDDEN / 4; idx += 256)
            sWv[idx] = Wv[idx];
    }
    __syncthreads();

    int row = blockIdx.x * 256 + threadIdx.x;
    if (row >= N_NODES) return;

    float acc[HIDDEN];
#pragma unroll
    for (int j = 0; j < HIDDEN; ++j) acc[j] = 0.0f;

    const float* xr = x + (size_t)row * F_IN;
#pragma unroll 4
    for (int k = 0; k < F_IN; k += 4) {
        float4 xv = *(const float4*)(xr + k);
        const float xs[4] = {xv.x, xv.y, xv.z, xv.w};
#pragma unroll
        for (int kk = 0; kk < 4; ++kk) {
            const float* wrow = &sW[(k + kk) * HIDDEN];
#pragma unroll
            for (int j = 0; j < HIDDEN; ++j)
                acc[j] = fmaf(xs[kk], wrow[j], acc[j]);
        }
    }

    float d = dis[row];
    float* h = h1s + (size_t)row * HIDDEN;
#pragma unroll
    for (int q = 0; q < 4; ++q) {
        float4 hv;
        hv.x = acc[q*4+0] * d;  hv.y = acc[q*4+1] * d;
        hv.z = acc[q*4+2] * d;  hv.w = acc[q*4+3] * d;
        *(float4*)(h + q*4) = hv;
    }
}

// ---- agg layer 1 (gather) + relu/b1 epilogue: g = relu(dis*(Σ h1s)+b1)*dis ----
// 4 threads per node; thread q owns float4 slice [q*4, q*4+4)
__global__ __launch_bounds__(256) void k_agg1(
        const int* __restrict__ offsets, const int* __restrict__ cnt,
        const int* __restrict__ csr, const float* __restrict__ dis,
        const float* __restrict__ b1,
        const float* __restrict__ h1s, float* __restrict__ g) {
    int t = blockIdx.x * 256 + threadIdx.x;
    if (t >= N_NODES * 4) return;
    int node = t >> 2;
    int q = t & 3;

    float4 acc = *(const float4*)(h1s + (size_t)node * HIDDEN + q * 4);  // self
    int start = offsets[node];
    int n = cnt[node];
    for (int i = 0; i < n; ++i) {
        int r = csr[start + i];
        float4 v = *(const float4*)(h1s + (size_t)r * HIDDEN + q * 4);
        acc.x += v.x; acc.y += v.y; acc.z += v.z; acc.w += v.w;
    }
    float d = dis[node];
    float4 bq = *(const float4*)(b1 + q * 4);
    float4 r;
    r.x = fmaxf(fmaf(acc.x, d, bq.x), 0.0f) * d;
    r.y = fmaxf(fmaf(acc.y, d, bq.y), 0.0f) * d;
    r.z = fmaxf(fmaf(acc.z, d, bq.z), 0.0f) * d;
    r.w = fmaxf(fmaf(acc.w, d, bq.w), 0.0f) * d;
    *(float4*)(g + (size_t)node * HIDDEN + q * 4) = r;
}

// ---- agg layer 2 (gather) + W2 matmul + b2: out = b2 + (dis*(Σ g)) @ W2 ----
__global__ __launch_bounds__(256) void k_agg2(
        const int* __restrict__ offsets, const int* __restrict__ cnt,
        const int* __restrict__ csr, const float* __restrict__ dis,
        const float* __restrict__ W2, const float* __restrict__ b2,
        const float* __restrict__ g, float* __restrict__ out) {
    __shared__ float sW[HIDDEN * N_CLS];   // 2560 B
    __shared__ float sb2[N_CLS];
    __shared__ float sAgg[64][HIDDEN];     // 4 KB: 64 nodes per block
    for (int idx = threadIdx.x; idx < HIDDEN * N_CLS; idx += 256) sW[idx] = W2[idx];
    if (threadIdx.x < N_CLS) sb2[threadIdx.x] = b2[threadIdx.x];
    __syncthreads();

    int t = blockIdx.x * 256 + threadIdx.x;
    int node = t >> 2;
    int q = t & 3;
    int ln = threadIdx.x >> 2;    // local node 0..63

    if (node < N_NODES) {
        float4 acc = *(const float4*)(g + (size_t)node * HIDDEN + q * 4);  // self
        int start = offsets[node];
        int n = cnt[node];
        for (int i = 0; i < n; ++i) {
            int r = csr[start + i];
            float4 v = *(const float4*)(g + (size_t)r * HIDDEN + q * 4);
            acc.x += v.x; acc.y += v.y; acc.z += v.z; acc.w += v.w;
        }
        float d = dis[node];
        sAgg[ln][q*4+0] = acc.x * d;
        sAgg[ln][q*4+1] = acc.y * d;
        sAgg[ln][q*4+2] = acc.z * d;
        sAgg[ln][q*4+3] = acc.w * d;
    }
    __syncthreads();
    if (node >= N_NODES) return;

    // thread q computes output columns [q*10, q*10+10)
    float a[HIDDEN];
#pragma unroll
    for (int j = 0; j < HIDDEN; ++j) a[j] = sAgg[ln][j];

    float* op = out + (size_t)node * N_CLS + q * 10;
#pragma unroll
    for (int k = 0; k < 10; ++k) {
        int col = q * 10 + k;
        float o = sb2[col];
#pragma unroll
        for (int j = 0; j < HIDDEN; ++j)
            o = fmaf(a[j], sW[j * N_CLS + col], o);
        op[k] = o;
    }
}

extern "C" void kernel_launch(void* const* d_in, const int* in_sizes, int n_in,
                              void* d_out, int out_size, void* d_ws, size_t ws_size,
                              hipStream_t stream) {
    const float* x  = (const float*)d_in[0];
    const int*   ei = (const int*)d_in[1];
    const float* W1 = (const float*)d_in[2];
    const float* b1 = (const float*)d_in[3];
    const float* W2 = (const float*)d_in[4];
    const float* b2 = (const float*)d_in[5];
    float* out = (float*)d_out;

    // ws layout (all 16B-aligned): cnt | offsets | cursor | blockSums(pad128) |
    //                              dis | csr | h1s | g      ≈ 21 MB
    char* w = (char*)d_ws;
    int*   cnt       = (int*)w;                      w += (size_t)N_NODES * 4;
    int*   offsets   = (int*)w;                      w += (size_t)N_NODES * 4;
    int*   cursor    = (int*)w;                      w += (size_t)N_NODES * 4;
    int*   blockSums = (int*)w;                      w += 128 * 4;
    float* dis       = (float*)w;                    w += (size_t)N_NODES * 4;
    int*   csr       = (int*)w;                      w += (size_t)N_EDGES * 4;
    float* h1s       = (float*)w;                    w += (size_t)N_NODES * HIDDEN * 4;
    float* g         = (float*)w;

    const int TB = 256;
    const int gN  = (N_NODES + TB - 1) / TB;
    const int gE  = (N_EDGES + TB - 1) / TB;
    const int gN4 = (N_NODES * 4 + TB - 1) / TB;

    k_zero <<<gN,  TB, 0, stream>>>(cnt);
    k_count<<<gE,  TB, 0, stream>>>(ei, cnt);
    k_scanA<<<NSB, TB, 0, stream>>>(cnt, blockSums);
    k_scanB<<<1,  128, 0, stream>>>(blockSums);
    k_scanC<<<NSB, TB, 0, stream>>>(cnt, blockSums, offsets, cursor, dis);
    k_fill <<<gE,  TB, 0, stream>>>(ei, cursor, csr);
    k_gemm1<<<gN,  TB, 0, stream>>>(x, W1, dis, h1s);
    k_agg1 <<<gN4, TB, 0, stream>>>(offsets, cnt, csr, dis, b1, h1s, g);
    k_agg2 <<<gN4, TB, 0, stream>>>(offsets, cnt, csr, dis, W2, b2, g, out);
}